// Round 3
// baseline (680.384 us; speedup 1.0000x reference)
//
#include <hip/hip_runtime.h>

// ResidualConvLSTM2D on MI355X (gfx950).
// Fused per-timestep implicit GEMM: z = conv3x3([x_t || h_{t-1}], [Wx || Wh]) via
// bf16 MFMA (16x16x32), fp32 LSTM cell, fp32 residual 1x1 conv.
//
// R6: R5 (44 us/dispatch) was barrier-drain bound: __syncthreads() compiles to
// s_waitcnt vmcnt(0) which drains the just-issued next-phase weight DMA, so all
// 14 phases pay full DMA latency serially (MfmaUtil 5.7%, BW 2.35 TB/s - no
// pipe near a wall). Fix = T3/T4 counted-vmcnt pipeline:
//  - TRIPLE-buffered weight tile; phase p issues DMA for p+2.
//  - raw __builtin_amdgcn_s_barrier + per-wave counted s_waitcnt vmcnt(N)
//    (N = own loads in flight for p+2); never vmcnt(0) in the loop. Each tile
//    gets 2 full phases of latency cover.
//  - sched_barrier(0) fences around the asm waits (rule #18), one full drain
//    in the prologue so in-loop vmcnt counts are exact (bias/patch loads all
//    retired before the loop).
//  - DMA: 40 chunks x 1KB per phase; waves 0-7 issue 3, waves 8-15 issue 2.
// Everything else (tiling, epilogue, c-in-out scheme) unchanged from R5.
//
// ws layout (<4.79 MB of ~8 MB):
//   [0, 573440)          WT staged bf16 [28][256][40] (step 27 zeroed)
//   [589824, +2MB)       h ping  bf16 [4][64][64][64]
//   [2686976, +2MB)      h pong  bf16
// Cell state c (fp32) lives inside d_out: c_t at out[b][t][...] (read before
// that address is overwritten with the output), c_{t+1} into slab t+1.
#define B_ 4
#define T_ 16
#define H_ 64
#define W_ 64
#define CIN 32
#define F_ 64
#define NCH 256
#define KSTEPS 27
#define NPHASE 14
#define WSTEP 10240           // shorts per K-step weight image [256][40]
#define PHS   20480           // shorts per phase (2 K-steps)
#define TSLAB (H_ * W_ * F_)  // floats between (b,t) and (b,t+1)

#define OFF_H0 589824
#define OFF_H1 2686976

typedef __attribute__((ext_vector_type(8))) short short8;
typedef __attribute__((ext_vector_type(4))) float floatx4;
typedef __attribute__((address_space(3))) unsigned int  lds_u32;
typedef __attribute__((address_space(1))) const unsigned int g_u32;

__device__ __forceinline__ unsigned short f2bf(float f) {
  union { float f; unsigned u; } v; v.f = f;
  unsigned r = v.u + 0x7FFFu + ((v.u >> 16) & 1u);   // round-to-nearest-even
  return (unsigned short)(r >> 16);
}

// tanh via hardware exp2: tanh(z) = 1 - 2/(exp(2z)+1). rcp approx (~1 ulp) is
// far inside the 4e-2 abs threshold. Saturates correctly for |z| large.
__device__ __forceinline__ float tanh_fast(float z) {
  float e = __expf(2.0f * z);
  return 1.0f - 2.0f * __builtin_amdgcn_rcpf(e + 1.0f);
}

// Staging image: WT[s][n][c], c in [0,40); c<32 -> weight for k = s*32+c of
// output channel n (k = tap*96 + ch; ch<32 from Wx else Wh); pad/step-27 -> 0.
__global__ void prep_weights(const float* __restrict__ Wx, const float* __restrict__ Wh,
                             unsigned short* __restrict__ WT) {
  int idx = blockIdx.x * 256 + threadIdx.x;            // 0..286719
  int s = idx / WSTEP;
  int r = idx - s * WSTEP;
  int n = r / 40;
  int c = r - n * 40;
  unsigned short v = 0;
  if (c < 32 && s < KSTEPS) {
    int k  = s * 32 + c;
    int g  = k / 96;
    int ch = k - g * 96;
    float f = (ch < CIN) ? Wx[(g * CIN + ch) * NCH + n]
                         : Wh[(g * F_ + (ch - CIN)) * NCH + n];
    v = f2bf(f);
  }
  WT[idx] = v;
}

// Zero h ping+pong (4 MB in ws).
__global__ void prep_zero_h(float4* __restrict__ p) {
  int idx = blockIdx.x * 256 + threadIdx.x;
  p[idx] = make_float4(0.f, 0.f, 0.f, 0.f);
}

// Zero c0 = out slabs [b][0][...].
__global__ void prep_zero_c(float* __restrict__ out) {
  int idx = blockIdx.x * 256 + threadIdx.x;            // float4 units
  int b = idx >> 16;
  int i = idx & 65535;
  ((float4*)(out + (size_t)b * (T_ * TSLAB)))[i] = make_float4(0.f, 0.f, 0.f, 0.f);
}

// Stage one phase's weight tile (2 K-steps, 40960 B) as 40 x 1KB chunks:
// waves 0-7 take 3 chunks (0..23), waves 8-15 take 2 (24..39).
// LDS dst is wave-uniform + lane*16.
__device__ __forceinline__ void stage_ph(const unsigned short* __restrict__ src,
                                         short* dstbuf, int w, int lane) {
  __attribute__((address_space(3))) unsigned short* d =
      (__attribute__((address_space(3))) unsigned short*)dstbuf;
  const unsigned short* s = src + lane * 8;
  if (w < 8) {
    #pragma unroll
    for (int i = 0; i < 3; i++) {
      int q = w * 3 + i;
      __builtin_amdgcn_global_load_lds((g_u32*)(s + q * 512),
                                       (lds_u32*)(d + q * 512), 16, 0, 0);
    }
  } else {
    #pragma unroll
    for (int i = 0; i < 2; i++) {
      int q = 24 + (w - 8) * 2 + i;
      __builtin_amdgcn_global_load_lds((g_u32*)(s + q * 512),
                                       (lds_u32*)(d + q * 512), 16, 0, 0);
    }
  }
}

__global__ __launch_bounds__(1024, 1)
void step_kernel(const float* __restrict__ x, const float* __restrict__ bias,
                 const float* __restrict__ Wp, const float* __restrict__ bp,
                 const unsigned short* __restrict__ WT,
                 const unsigned short* __restrict__ hprev,
                 unsigned short* __restrict__ hnew,
                 float* __restrict__ out, int t)
{
  // LDS: patch [4][34][104] sh (28288) | 3 x weight buf [2][256][40] sh (40960).
  // epilogue reuse: gact [256][68] fp32 (69632 B) at 0, WpL 8 KB at 69632.
  __shared__ __align__(16) char smem[151168];
  short* patch = (short*)smem;
  short* wb0   = (short*)(smem + 28288);
  short* wb1   = (short*)(smem + 69248);
  short* wb2   = (short*)(smem + 110208);
  float* gact  = (float*)smem;
  float* WpL   = (float*)(smem + 69632);

  const int tid  = threadIdx.x;
  const int w    = tid >> 6;               // 0..15
  const int lane = tid & 63;
  const int quad = lane >> 4;
  const int lr   = lane & 15;
  const int gate = w >> 2;                 // wave's gate (i,f,c,o)
  const int mq   = w & 3;                  // wave's M-quarter (16 pixels)

  // bijective XCD swizzle: 256 blocks, 8 XCDs, 32 consecutive bids per XCD.
  const int raw = blockIdx.x;
  const int bid = (raw & 7) * 32 + (raw >> 3);
  const int b   = bid >> 6;
  const int rem = bid & 63;
  const int y0  = (rem >> 1) << 1;   // 2-row tile
  const int x0  = (rem & 1) << 5;    // 32-col half

  // ---- prefetch phase-0 weights into wb0 (in flight during patch staging)
  stage_ph(WT, wb0, w, lane);

  // ---- stage input patch: 4 rows x 34 cols x 96 ch (x bf16 | h bf16),
  // split per entry into x-half / h-half across 272 threads.
  if (tid < 272) {
    int e = tid >> 1, half = tid & 1;
    int sy = e / 34, sx = e - sy * 34;
    int yy = y0 + sy - 1, xx = x0 + sx - 1;
    short* dst = patch + e * 104;
    bool in = (yy >= 0 && yy < H_ && xx >= 0 && xx < W_);
    if (half == 0) {                      // x channels 0..31 -> bf16
      if (in) {
        const float4* xs = (const float4*)(x + ((((b * T_ + t) * H_ + yy) * W_ + xx) * CIN));
        #pragma unroll
        for (int j = 0; j < 4; j++) {
          float4 f0 = xs[2 * j];
          float4 f1 = xs[2 * j + 1];
          union { short8 v; unsigned short u[8]; } pk;
          pk.u[0] = f2bf(f0.x); pk.u[1] = f2bf(f0.y); pk.u[2] = f2bf(f0.z); pk.u[3] = f2bf(f0.w);
          pk.u[4] = f2bf(f1.x); pk.u[5] = f2bf(f1.y); pk.u[6] = f2bf(f1.z); pk.u[7] = f2bf(f1.w);
          ((short8*)dst)[j] = pk.v;
        }
      } else {
        uint4 z = make_uint4(0, 0, 0, 0);
        uint4* d4 = (uint4*)dst;
        #pragma unroll
        for (int j = 0; j < 4; j++) d4[j] = z;
      }
    } else {                              // h channels (already bf16)
      uint4* d2 = (uint4*)(dst + 32);
      if (in) {
        const uint4* hs = (const uint4*)(hprev + ((b * H_ + yy) * W_ + xx) * F_);
        #pragma unroll
        for (int j = 0; j < 8; j++) d2[j] = hs[j];
      } else {
        uint4 z = make_uint4(0, 0, 0, 0);
        #pragma unroll
        for (int j = 0; j < 8; j++) d2[j] = z;
      }
    }
  }

  // ---- prefetch phase-1 weights into wb1
  stage_ph(WT + PHS, wb1, w, lane);

  float bias_r[4];
  #pragma unroll
  for (int nf = 0; nf < 4; nf++) bias_r[nf] = bias[gate * 64 + nf * 16 + lr];

  floatx4 acc[4];
  #pragma unroll
  for (int nf = 0; nf < 4; nf++) acc[nf] = (floatx4){0.f, 0.f, 0.f, 0.f};

  // wave's A-row (pixel) for the MFMA A operand
  const int px = mq * 16 + lr;            // 0..63
  const int ty = px >> 5, tx = px & 31;

  // ---- one full drain (prologue only): patch loads/writes + P0,P1 DMA + bias
  // all retired, so in-loop vmcnt counts are exact.
  asm volatile("s_waitcnt vmcnt(0) lgkmcnt(0)" ::: "memory");
  __builtin_amdgcn_sched_barrier(0);
  __builtin_amdgcn_s_barrier();
  __builtin_amdgcn_sched_barrier(0);

  // ---- K loop: 14 phases of 2 K-steps (BK=64) over K=864; TRIPLE-buffered
  // weight tile, DMA issued 2 phases ahead, counted vmcnt (never 0) so the
  // p+2 prefetch stays in flight across the phase barrier.
  short* b0 = wb0;   // compute tile (phase p)
  short* b1 = wb1;   // landed-or-landing tile (phase p+1)
  short* b2 = wb2;   // DMA target (phase p+2)
  const unsigned short* wsrc = WT + 2 * PHS;
  for (int p = 0; p < NPHASE; p++) {
    if (p < NPHASE - 2) {
      stage_ph(wsrc, b2, w, lane);
      wsrc += PHS;
    }
    int s0 = 2 * p;
    #pragma unroll
    for (int half = 0; half < 2; half++) {
      int s = s0 + half;
      if (s < KSTEPS) {
        int g  = s / 3;
        int c0 = (s - g * 3) * 32;
        int dy = g / 3, dx = g - dy * 3;
        short8 afr = *(const short8*)(patch + ((ty + dy) * 34 + tx + dx) * 104 + c0 + quad * 8);
        #pragma unroll
        for (int nf = 0; nf < 4; nf++) {
          short8 bfr = *(const short8*)(b0 + half * WSTEP + (gate * 64 + nf * 16 + lr) * 40 + quad * 8);
          acc[nf] = __builtin_amdgcn_mfma_f32_16x16x32_bf16(afr, bfr, acc[nf], 0, 0, 0);
        }
      }
    }
    // end-of-phase: guarantee p+1's tile landed; leave p+2's DMA in flight.
    __builtin_amdgcn_sched_barrier(0);
    if (p < NPHASE - 2) {
      if (w < 8) asm volatile("s_waitcnt vmcnt(3)" ::: "memory");
      else       asm volatile("s_waitcnt vmcnt(2)" ::: "memory");
    } else {
      asm volatile("s_waitcnt vmcnt(0)" ::: "memory");
    }
    __builtin_amdgcn_sched_barrier(0);
    __builtin_amdgcn_s_barrier();
    __builtin_amdgcn_sched_barrier(0);
    { short* tmp = b0; b0 = b1; b1 = b2; b2 = tmp; }
  }

  // ---- epilogue phase 1: activations -> gact[(gate*64+px)*68 + ch], WpL
  #pragma unroll
  for (int nf = 0; nf < 4; nf++)
    #pragma unroll
    for (int r = 0; r < 4; r++) {
      int mm = quad * 4 + r;                      // D row = quad*4 + reg
      float z = acc[nf][r] + bias_r[nf];
      float a;
      if (gate == 2) a = tanh_fast(z);            // candidate gate
      else {                                      // hard_sigmoid for i, f, o
        a = __builtin_fmaf(z, 0.2f, 0.5f);
        a = fminf(fmaxf(a, 0.f), 1.f);
      }
      gact[(gate * 64 + mq * 16 + mm) * 68 + nf * 16 + lr] = a;
    }
  if (tid < 512)                                  // Wp -> LDS (512 float4)
    ((float4*)WpL)[tid] = ((const float4*)Wp)[tid];

  const int mloc = tid >> 4;                      // pixel in tile (0..63)
  const int cb   = (tid & 15) * 4;                // 4-channel slice
  const int tyo  = mloc >> 5, txo = mloc & 31;
  const int gy   = y0 + tyo, gx = x0 + txo;
  const int hbase   = ((b * H_ + gy) * W_ + gx) * F_ + cb;
  const int outbase = (((b * T_ + t) * H_ + gy) * W_ + gx) * F_ + cb;

  // prefetch x (residual) and c_t (global) before the barrier
  float xv[32];
  {
    const float4* xs = (const float4*)(x + ((((b * T_ + t) * H_ + gy) * W_ + gx) * CIN));
    #pragma unroll
    for (int j = 0; j < 8; j++) {
      float4 f = xs[j];
      xv[4 * j] = f.x; xv[4 * j + 1] = f.y; xv[4 * j + 2] = f.z; xv[4 * j + 3] = f.w;
    }
  }
  float4 co4 = *(const float4*)(out + outbase);

  __syncthreads();                                // gact + WpL visible

  // ---- residual 1x1 conv (fp32), 4 output channels per thread
  float res[4];
  #pragma unroll
  for (int j = 0; j < 4; j++) res[j] = bp[cb + j];
  #pragma unroll
  for (int ci = 0; ci < 32; ci++) {
    float xf = xv[ci];
    float4 wv = *(const float4*)(WpL + ci * 64 + cb);
    res[0] += xf * wv.x; res[1] += xf * wv.y; res[2] += xf * wv.z; res[3] += xf * wv.w;
  }

  // ---- LSTM cell combine (4 channels per thread)
  float4 gi = *(const float4*)(gact + (0 * 64 + mloc) * 68 + cb);
  float4 gf = *(const float4*)(gact + (1 * 64 + mloc) * 68 + cb);
  float4 gg = *(const float4*)(gact + (2 * 64 + mloc) * 68 + cb);
  float4 go = *(const float4*)(gact + (3 * 64 + mloc) * 68 + cb);
  float cold[4] = {co4.x, co4.y, co4.z, co4.w};
  float iv[4] = {gi.x, gi.y, gi.z, gi.w};
  float fv[4] = {gf.x, gf.y, gf.z, gf.w};
  float gv[4] = {gg.x, gg.y, gg.z, gg.w};
  float ov[4] = {go.x, go.y, go.z, go.w};
  float cn4[4], h4[4];
  union { unsigned short hv[4]; uint2 q; } hu;
  #pragma unroll
  for (int e = 0; e < 4; e++) {
    float cn = fv[e] * cold[e] + iv[e] * gv[e];
    float h  = ov[e] * tanh_fast(cn);
    cn4[e] = cn; h4[e] = h;
    hu.hv[e] = f2bf(h);
  }
  if (t < T_ - 1)                                 // c_{t+1} -> next out slab
    *(float4*)(out + outbase + TSLAB) = make_float4(cn4[0], cn4[1], cn4[2], cn4[3]);
  *(float4*)(out + outbase) = make_float4(h4[0] + res[0], h4[1] + res[1],
                                          h4[2] + res[2], h4[3] + res[3]);
  *(uint2*)(hnew + hbase) = hu.q;
}

extern "C" void kernel_launch(void* const* d_in, const int* in_sizes, int n_in,
                              void* d_out, int out_size, void* d_ws, size_t ws_size,
                              hipStream_t stream) {
  const float* x    = (const float*)d_in[0];
  const float* Wx   = (const float*)d_in[1];
  const float* Wh   = (const float*)d_in[2];
  const float* bias = (const float*)d_in[3];
  const float* Wp   = (const float*)d_in[4];
  const float* bp   = (const float*)d_in[5];
  float* out = (float*)d_out;

  unsigned short* WT = (unsigned short*)d_ws;
  unsigned short* h0 = (unsigned short*)((char*)d_ws + OFF_H0);
  unsigned short* h1 = (unsigned short*)((char*)d_ws + OFF_H1);

  hipLaunchKernelGGL(prep_weights, dim3(1120), dim3(256), 0, stream, Wx, Wh, WT);
  hipLaunchKernelGGL(prep_zero_h, dim3(1024), dim3(256), 0, stream,
                     (float4*)((char*)d_ws + OFF_H0));
  hipLaunchKernelGGL(prep_zero_c, dim3(1024), dim3(256), 0, stream, out);

  for (int t = 0; t < T_; t++) {
    const unsigned short* hp = (t & 1) ? h1 : h0;
    unsigned short*       hn = (t & 1) ? h0 : h1;
    hipLaunchKernelGGL(step_kernel, dim3(256), dim3(1024), 0, stream,
                       x, bias, Wp, bp, WT, hp, hn, out, t);
  }
}